// Round 4
// baseline (44.219 us; speedup 1.0000x reference)
//
#include <hip/hip_runtime.h>

// Problem constants (match reference setup_inputs)
#define BATCH   32
#define NCLS    80
#define MAXB    50
#define NANCH   12288                   // 3*64*64 anchors per image
#define BLK     256
#define BLKS_PER_IMG 48                 // NANCH / BLK
#define TOTAL_BLKS (BATCH * BLKS_PER_IMG)  // 1536
#define ROWLEN  85                      // NCLS + 5

// Fused kernel: per-anchor IoU matching + BCE + grid-wide finalize.
// Division-free IoU compare (cross-multiplication; unions always > 0).
// Last-finished block performs the final per-image reduction (atomic
// counter in d_ws, zeroed by a hipMemsetAsync node every launch).
__global__ __launch_bounds__(BLK) void yolo_fused(
    const float* __restrict__ pred,      // (B, NANCH, 85)
    const float* __restrict__ ann,       // (B, MAXB, 5)
    const float* __restrict__ anchors,   // (NANCH, 4)
    float2*      __restrict__ psum,      // (TOTAL_BLKS): (sum, count)
    int*         __restrict__ counter,   // zeroed each launch
    float*       __restrict__ out)       // (2, B)
{
    const int blk = blockIdx.x;                 // 0..47
    const int b   = blockIdx.y;                 // image
    const int n   = blk * BLK + threadIdx.x;    // anchor index

    // Annotation tiles: corners only. Invalid anns (cls==-1) collapse to a
    // degenerate point at 5e17: inter==0 exactly, area_b==0 -> union=area_a,
    // fraction 0 -> never updates best, never positive. Loss-equivalent to
    // the reference's iou=-1 masking (class of a never-positive anchor is
    // never consumed).
    __shared__ float4 s_box[MAXB];   // x1,y1,x2,y2
    __shared__ float  s_cls[MAXB];
    if (threadIdx.x < MAXB) {
        const float* a = ann + ((size_t)b * MAXB + threadIdx.x) * 5;
        const float cx = a[0], cy = a[1], w = a[2], h = a[3], cl = a[4];
        float x1 = cx - w * 0.5f, y1 = cy - h * 0.5f;
        float x2 = cx + w * 0.5f, y2 = cy + h * 0.5f;
        if (cl == -1.0f) { x1 = y1 = x2 = y2 = 5e17f; }
        s_box[threadIdx.x] = make_float4(x1, y1, x2, y2);
        s_cls[threadIdx.x] = cl;
    }
    __syncthreads();

    const float4 a4 = *reinterpret_cast<const float4*>(anchors + (size_t)n * 4);
    const float ax1 = a4.x - a4.z * 0.5f, ay1 = a4.y - a4.w * 0.5f;
    const float ax2 = a4.x + a4.z * 0.5f, ay2 = a4.y + a4.w * 0.5f;
    const float area_a = (ax2 - ax1) * (ay2 - ay1);

    float bi = 0.0f, bu = 1.0f;   // best IoU fraction bi/bu
    int   bestm = 0;
    #pragma unroll 10
    for (int m = 0; m < MAXB; ++m) {
        const float4 bb = s_box[m];
        float iw = fminf(ax2, bb.z) - fmaxf(ax1, bb.x); iw = fmaxf(iw, 0.0f);
        float ih = fminf(ay2, bb.w) - fmaxf(ay1, bb.y); ih = fmaxf(ih, 0.0f);
        const float inter  = iw * ih;
        const float area_b = (bb.z - bb.x) * (bb.w - bb.y);
        const float ua     = area_a + area_b - inter;   // >= area_a >= 256 for updates
        // strict > keeps first occurrence, matching jnp.argmax
        if (inter * bu > bi * ua) { bi = inter; bu = ua; bestm = m; }
    }

    const bool positive = (2.0f * bi >= bu);   // iou >= 0.5
    float local = 0.0f;
    if (positive) {
        const int ac = (int)fminf(fmaxf(s_cls[bestm], 0.0f), (float)(NCLS - 1));
        const float* prow = pred + ((size_t)b * NANCH + n) * ROWLEN + 5;
        // BCE vs one-hot: -log(p[ac]) + log(1-p[ac]) - sum_c log(1-p[c])
        // sum of logs -> 5 chunked log-of-products (p in (.01,.99): no underflow)
        float S = 0.0f;
        #pragma unroll
        for (int ch = 0; ch < 5; ++ch) {
            float prod = 1.0f;
            #pragma unroll
            for (int j = 0; j < 16; ++j) {
                const float p = prow[ch * 16 + j];
                prod = __builtin_fmaf(-p, prod, prod);   // prod *= (1 - p)
            }
            S += __logf(prod);
        }
        const float pa = prow[ac];
        local = -__logf(pa) + __logf(1.0f - pa) - S;
    }

    // Deterministic block reduction: wave shuffle then cross-wave via LDS
    float v = local;
    float c = positive ? 1.0f : 0.0f;
    #pragma unroll
    for (int off = 32; off > 0; off >>= 1) {
        v += __shfl_down(v, off, 64);
        c += __shfl_down(c, off, 64);
    }
    __shared__ float2 s_part[BLK / 64];
    const int wave = threadIdx.x >> 6;
    if ((threadIdx.x & 63) == 0) s_part[wave] = make_float2(v, c);
    __syncthreads();

    __shared__ int s_done;
    if (threadIdx.x == 0) {
        float t = 0.0f, tc = 0.0f;
        #pragma unroll
        for (int w = 0; w < BLK / 64; ++w) { t += s_part[w].x; tc += s_part[w].y; }
        psum[b * BLKS_PER_IMG + blk] = make_float2(t, tc);
        __threadfence();   // release: partial visible before counter bump
        const int old = atomicAdd(counter, 1);   // device-scope by default
        s_done = (old == TOTAL_BLKS - 1) ? 1 : 0;
    }
    __syncthreads();
    if (!s_done) return;

    // ---- finisher: last block reduces all partials (deterministic order) ----
    __threadfence();   // acquire: all partials visible
    const int t2  = threadIdx.x;          // 256 threads
    const int img = t2 >> 3;              // 0..31
    const int j   = t2 & 7;               // 0..7
    float fv = 0.0f, fc = 0.0f;
    #pragma unroll
    for (int k = 0; k < BLKS_PER_IMG / 8; ++k) {
        const float2 p2 = psum[img * BLKS_PER_IMG + k * 8 + j];
        fv += p2.x; fc += p2.y;
    }
    fv += __shfl_down(fv, 4, 8); fc += __shfl_down(fc, 4, 8);
    fv += __shfl_down(fv, 2, 8); fc += __shfl_down(fc, 2, 8);
    fv += __shfl_down(fv, 1, 8); fc += __shfl_down(fc, 1, 8);
    if (j == 0) {
        out[img]         = fv / fmaxf(fc, 1.0f);  // cls_loss
        out[BATCH + img] = 0.0f;                  // reg_loss (no-op in source)
    }
}

extern "C" void kernel_launch(void* const* d_in, const int* in_sizes, int n_in,
                              void* d_out, int out_size, void* d_ws, size_t ws_size,
                              hipStream_t stream) {
    const float* pred    = (const float*)d_in[0];   // (B, A, G, G, 85)
    const float* ann     = (const float*)d_in[1];   // (B, MAXB, 5)
    const float* anchors = (const float*)d_in[2];   // (A, G, G, 4)
    float* out = (float*)d_out;

    float2* psum    = (float2*)d_ws;
    int*    counter = (int*)((char*)d_ws + sizeof(float2) * TOTAL_BLKS);

    // zero the completion counter every call (graph-capturable node)
    (void)hipMemsetAsync(counter, 0, sizeof(int), stream);

    dim3 grid(BLKS_PER_IMG, BATCH);
    yolo_fused<<<grid, BLK, 0, stream>>>(pred, ann, anchors, psum, counter, out);
}

// Round 5
// 17.496 us; speedup vs baseline: 2.5273x; 2.5273x over previous
//
#include <hip/hip_runtime.h>

// Problem constants (match reference setup_inputs)
#define BATCH   32
#define NCLS    80
#define MAXB    50
#define NANCH   12288                   // 3*64*64 anchors per image
#define BLK     256
#define BLKS_PER_IMG 48                 // NANCH / BLK
#define ROWLEN  85                      // NCLS + 5

// Kernel 1: per-anchor IoU matching + BCE for positive anchors.
// Prologue compacts the valid annotations (cls != -1) order-preservingly via
// wave ballot; the match loop then runs only over valid boxes (~60% of 50).
// Compaction is loss-equivalent to the reference's iou=-1 masking:
//  - argmax is only consumed when positive (iou>=0.5), which requires a
//    valid box with inter>0; order-preserving compaction keeps the
//    first-occurrence winner identical.
//  - no valid boxes -> loop empty -> no positives -> loss 0 (matches
//    reference's has_ann gate).
__global__ __launch_bounds__(BLK) void yolo_match_bce(
    const float* __restrict__ pred,      // (B, NANCH, 85)
    const float* __restrict__ ann,       // (B, MAXB, 5)
    const float* __restrict__ anchors,   // (NANCH, 4)
    float* __restrict__ psum,            // (B, BLKS_PER_IMG)
    int*   __restrict__ pcnt)            // (B, BLKS_PER_IMG)
{
    const int blk = blockIdx.x;                 // 0..47
    const int b   = blockIdx.y;                 // image
    const int n   = blk * BLK + threadIdx.x;    // anchor index

    __shared__ float4 s_box[MAXB];   // compacted corners x1,y1,x2,y2
    __shared__ float  s_area[MAXB];  // compacted box area
    __shared__ float  s_cls[MAXB];   // compacted class
    __shared__ int    s_nv;          // number of valid boxes

    // Wave-0 (lanes 0..49) compacts the annotation list.
    if (threadIdx.x < 64) {
        const int lane = threadIdx.x;
        float cx = 0, cy = 0, w = 0, h = 0, cl = -1.0f;
        if (lane < MAXB) {
            const float* a = ann + ((size_t)b * MAXB + lane) * 5;
            cx = a[0]; cy = a[1]; w = a[2]; h = a[3]; cl = a[4];
        }
        const bool valid = (lane < MAXB) && (cl != -1.0f);
        const unsigned long long mask = __ballot(valid);
        if (valid) {
            const int cidx = __popcll(mask & ((1ull << lane) - 1ull));
            const float x1 = cx - w * 0.5f, y1 = cy - h * 0.5f;
            const float x2 = cx + w * 0.5f, y2 = cy + h * 0.5f;
            s_box[cidx]  = make_float4(x1, y1, x2, y2);
            s_area[cidx] = (x2 - x1) * (y2 - y1);
            s_cls[cidx]  = cl;
        }
        if (lane == 0) s_nv = __popcll(mask);
    }
    __syncthreads();

    const float4 a4 = *reinterpret_cast<const float4*>(anchors + (size_t)n * 4);
    const float ax1 = a4.x - a4.z * 0.5f, ay1 = a4.y - a4.w * 0.5f;
    const float ax2 = a4.x + a4.z * 0.5f, ay2 = a4.y + a4.w * 0.5f;
    const float area_a = (ax2 - ax1) * (ay2 - ay1);

    const int nv = s_nv;
    float best = 0.0f;     // best IoU so far (all IoUs >= 0)
    int   bestm = 0;
    #pragma unroll 5
    for (int m = 0; m < nv; ++m) {
        const float4 bb = s_box[m];                 // LDS broadcast reads
        float iw = fminf(ax2, bb.z) - fmaxf(ax1, bb.x); iw = fmaxf(iw, 0.0f);
        float ih = fminf(ay2, bb.w) - fmaxf(ay1, bb.y); ih = fmaxf(ih, 0.0f);
        const float inter = iw * ih;
        const float ua    = area_a + s_area[m] - inter;  // >= area_a >= 256
        const float iou   = inter * __builtin_amdgcn_rcpf(ua);
        // strict > keeps first occurrence, matching jnp.argmax
        if (iou > best) { best = iou; bestm = m; }
    }

    const bool positive = (best >= 0.5f);
    float local = 0.0f;
    if (positive) {
        const int ac = (int)fminf(fmaxf(s_cls[bestm], 0.0f), (float)(NCLS - 1));
        const float* prow = pred + ((size_t)b * NANCH + n) * ROWLEN + 5;
        // BCE vs one-hot: -log(p[ac]) + log(1-p[ac]) - sum_c log(1-p[c])
        // sum of logs -> 5 chunked log-of-products (p in (.01,.99): no underflow)
        float S = 0.0f;
        #pragma unroll
        for (int ch = 0; ch < 5; ++ch) {
            float prod = 1.0f;
            #pragma unroll
            for (int j = 0; j < 16; ++j) {
                const float p = prow[ch * 16 + j];
                prod = __builtin_fmaf(-p, prod, prod);   // prod *= (1 - p)
            }
            S += __logf(prod);
        }
        const float pa = prow[ac];
        local = -__logf(pa) + __logf(1.0f - pa) - S;
    }

    // Deterministic block reduction: wave shuffle then cross-wave via LDS
    float v = local;
    int   c = positive ? 1 : 0;
    #pragma unroll
    for (int off = 32; off > 0; off >>= 1) {
        v += __shfl_down(v, off, 64);
        c += __shfl_down(c, off, 64);
    }
    __shared__ float s_sum[BLK / 64];
    __shared__ int   s_cnt[BLK / 64];
    const int wave = threadIdx.x >> 6;
    if ((threadIdx.x & 63) == 0) { s_sum[wave] = v; s_cnt[wave] = c; }
    __syncthreads();
    if (threadIdx.x == 0) {
        float t = 0.0f; int tc = 0;
        #pragma unroll
        for (int w = 0; w < BLK / 64; ++w) { t += s_sum[w]; tc += s_cnt[w]; }
        psum[b * BLKS_PER_IMG + blk] = t;
        pcnt[b * BLKS_PER_IMG + blk] = tc;
    }
}

// Kernel 2: reduce 48 partials per image -> final losses; write all outputs.
__global__ __launch_bounds__(64) void yolo_finalize(
    const float* __restrict__ psum,
    const int*   __restrict__ pcnt,
    float* __restrict__ out)             // (2, B): [cls_losses; reg_losses=0]
{
    const int b = blockIdx.x;
    const int t = threadIdx.x;           // 64 threads
    float v = (t < BLKS_PER_IMG) ? psum[b * BLKS_PER_IMG + t] : 0.0f;
    int   c = (t < BLKS_PER_IMG) ? pcnt[b * BLKS_PER_IMG + t] : 0;
    #pragma unroll
    for (int off = 32; off > 0; off >>= 1) {
        v += __shfl_down(v, off, 64);
        c += __shfl_down(c, off, 64);
    }
    if (t == 0) {
        const int np = (c > 1) ? c : 1;
        out[b]         = v / (float)np;  // cls_loss
        out[BATCH + b] = 0.0f;           // reg_loss (no-op branch in source)
    }
}

extern "C" void kernel_launch(void* const* d_in, const int* in_sizes, int n_in,
                              void* d_out, int out_size, void* d_ws, size_t ws_size,
                              hipStream_t stream) {
    const float* pred    = (const float*)d_in[0];   // (B, A, G, G, 85)
    const float* ann     = (const float*)d_in[1];   // (B, MAXB, 5)
    const float* anchors = (const float*)d_in[2];   // (A, G, G, 4)
    float* out = (float*)d_out;

    float* psum = (float*)d_ws;
    int*   pcnt = (int*)((char*)d_ws + sizeof(float) * BATCH * BLKS_PER_IMG);

    dim3 grid1(BLKS_PER_IMG, BATCH);
    yolo_match_bce<<<grid1, BLK, 0, stream>>>(pred, ann, anchors, psum, pcnt);
    yolo_finalize<<<BATCH, 64, 0, stream>>>(psum, pcnt, out);
}